// Round 9
// baseline (35.283 us; speedup 1.0000x reference)
//
#include <hip/hip_runtime.h>
#include <hip/hip_bf16.h>

#define C_IN  32
#define C_OUT 64
#define HH    64
#define WW    64

typedef __attribute__((ext_vector_type(4))) short short4v;
typedef __attribute__((ext_vector_type(8))) short short8v;
typedef __attribute__((ext_vector_type(4))) float f32x4;

static __device__ __forceinline__ unsigned short f2bf(float f) {
    unsigned u = __builtin_bit_cast(unsigned, f);
    unsigned r = (u + 0x7FFFu + ((u >> 16) & 1u)) >> 16;   // RNE
    return (unsigned short)r;
}
static __device__ __forceinline__ float bf2f(unsigned short b) {
    unsigned u = ((unsigned)b) << 16;
    return __builtin_bit_cast(float, u);
}

#if defined(__has_builtin)
#  if __has_builtin(__builtin_amdgcn_mfma_f32_16x16x16bf16_1k)
#    define HAVE_MFMA16_BUILTIN 1
#  endif
#endif

static __device__ __forceinline__ f32x4 mfma16(short4v a, short4v b, f32x4 c) {
#ifdef HAVE_MFMA16_BUILTIN
    return __builtin_amdgcn_mfma_f32_16x16x16bf16_1k(a, b, c, 0, 0, 0);
#else
    asm("v_mfma_f32_16x16x16_bf16 %0, %1, %2, %0" : "+v"(c) : "v"(a), "v"(b));
    return c;
#endif
}

#if defined(__has_builtin) && __has_builtin(__builtin_amdgcn_global_atomic_fadd_f32)
#define ATOMIC_FADD(p, v) unsafeAtomicAdd((p), (v))
#else
#define ATOMIC_FADD(p, v) atomicAdd((p), (v))
#endif

// ---------------------------------------------------------------------------
// Weight-product + B-fragment pack for 16x16x16 (K=16 = one ic-half).
// W~_k = Ew(k) * (w_k if (p+k) odd), Ew(k) = prod_{j>=k, (p+j) even} w_j
// Bpk[p][ih][k(9)][oct(4)][lane(64)][part(2)][j(4)]  (bf16, 16B per lane)
//   lane = (icl>>2)*16 + (oc&15), j = icl&3, icl = ic&15, ih = ic>>4
//   part 0 = hi, part 1 = lo. Total 147,456 bytes in d_ws.
// ---------------------------------------------------------------------------
__global__ void wprod_pack(const float* __restrict__ w, unsigned short* __restrict__ Bpk) {
    int t = blockIdx.x * 256 + threadIdx.x;
    if (t >= 2 * C_IN * C_OUT) return;
    int oc = t & 63;
    int ic = (t >> 6) & 31;
    int p  = t >> 11;
    const float* wp = w + (oc * C_IN + ic) * 9;
    float W[9];
    float Ew = 1.f;
    #pragma unroll
    for (int k = 8; k >= 0; --k) {
        float wk = wp[k];
        if (((p + k) & 1) == 0) { Ew *= wk; W[k] = Ew; }
        else                    { W[k] = wk * Ew; }
    }
    int ih   = ic >> 4;
    int icl  = ic & 15;
    int lane = ((icl >> 2) << 4) + (oc & 15);
    int j    = icl & 3;
    int oct  = oc >> 4;
    #pragma unroll
    for (int k = 0; k < 9; ++k) {
        unsigned short hi = f2bf(W[k]);
        unsigned short lo = f2bf(W[k] - bf2f(hi));
        size_t base = ((((size_t)(p * 2 + ih) * 9 + k) * 4 + oct) * 64 + lane) * 8;
        Bpk[base + 0 + j] = hi;
        Bpk[base + 4 + j] = lo;
    }
}

// ---------------------------------------------------------------------------
// GEMM body (parity compile-time). xt[a][k]: taps for this lane's 4 ics.
// 3-term split GEMM: C = Xh*Wh + Xl*Wh + Xh*Wl  (Xl*Wl ~ 2^-18, dropped).
// ---------------------------------------------------------------------------
template<int P>
__device__ __forceinline__ void aeg_gemm(
    float (&xt)[4][9], const short8v* __restrict__ Bq,
    float* __restrict__ cs, int ih, int grp, int l)
{
    // X~: suffix products of odd-step x's; even steps multiply own x.
    #pragma unroll
    for (int a = 0; a < 4; ++a) {
        float Ox = 1.f;
        #pragma unroll
        for (int k = 8; k >= 0; --k) {
            if (((P + k) & 1) == 1) { Ox *= xt[a][k]; xt[a][k] = Ox; }
            else                    { xt[a][k] = xt[a][k] * Ox; }
        }
    }

    f32x4 acc[4];
    #pragma unroll
    for (int t = 0; t < 4; ++t) acc[t] = (f32x4){0.f, 0.f, 0.f, 0.f};

    const int pb = (P * 2 + ih) * 9;

    #pragma unroll
    for (int k = 0; k < 9; ++k) {
        short4v ah, al;
        #pragma unroll
        for (int a = 0; a < 4; ++a) {
            float v  = xt[a][k];
            __hip_bfloat16 bh = __float2bfloat16(v);          // RNE
            float fh = __bfloat162float(bh);
            __hip_bfloat16 bl = __float2bfloat16(v - fh);
            ah[a] = (short)__builtin_bit_cast(unsigned short, bh);
            al[a] = (short)__builtin_bit_cast(unsigned short, bl);
        }
#ifndef HAVE_MFMA16_BUILTIN
        asm volatile("s_nop 1" ::: );   // VALU->MFMA src hazard guard (asm path)
#endif
        #pragma unroll
        for (int t = 0; t < 4; ++t) {
            short8v b = Bq[((size_t)(pb + k) * 4 + t) * 64 + l];   // hi(4) | lo(4)
            short4v bh = __builtin_shufflevector(b, b, 0, 1, 2, 3);
            short4v bl = __builtin_shufflevector(b, b, 4, 5, 6, 7);
            acc[t] = mfma16(ah, bh, acc[t]);
            acc[t] = mfma16(al, bh, acc[t]);
            acc[t] = mfma16(ah, bl, acc[t]);
        }
    }

#ifndef HAVE_MFMA16_BUILTIN
    asm volatile("s_nop 7\n\ts_nop 7" ::: );  // MFMA->VALU read hazard guard
#endif

    // Stage C into LDS: cs[oc][ii*64+jj], stride 130 (2-way bank alias = free).
    int colc = l & 15;
    int rgrp = l >> 4;
    #pragma unroll
    for (int t = 0; t < 4; ++t) {
        int oc = t * 16 + colc;
        #pragma unroll
        for (int r = 0; r < 4; ++r) {
            int q  = grp * 16 + rgrp * 4 + r;
            int ii = q >> 5;
            int jj = 2 * (q & 31) + ((ii + P) & 1);   // i0 even -> (i0+ii+P)&1 == (ii+P)&1
            cs[oc * 130 + ii * 64 + jj] = acc[t][r];
        }
    }
}

// ---------------------------------------------------------------------------
// Main kernel: block = 1 n x 2 rows x 64 cols x 16 ic (half), 512 thr = 8
// waves. Wave w: parity p = w&1, M-group grp = w>>1. Lane l: A-row =
// grp*16+(l&15) -> (i,j); K-elems = ic_local (l>>4)*4 + j (K=16 MFMA).
// Grid 512 = 2 blocks/CU = 4 waves/SIMD (2x TLP vs K=32 version).
// Epilogue: LDS-staged C tile -> coalesced atomic adds (4 lines/inst vs 64).
// ---------------------------------------------------------------------------
__global__ __launch_bounds__(512, 4) void aeg_mfma(
    const float* __restrict__ x, const unsigned short* __restrict__ Bpk,
    float* __restrict__ out)
{
    __shared__ float cs[C_OUT * 130];

    int bid = blockIdx.x;
    int br  = bid & 31;          // row-block (0..31), 2 rows each
    int n   = (bid >> 5) & 7;    // batch
    int ih  = bid >> 8;          // ic half (0..1)
    int i0  = br * 2;
    int tid = threadIdx.x;
    int w   = __builtin_amdgcn_readfirstlane(tid >> 6);  // wave 0..7
    int p   = w & 1;
    int grp = w >> 1;            // 0..3
    int l   = tid & 63;

    int qA = grp * 16 + (l & 15);
    int iA = i0 + (qA >> 5);
    int jA = 2 * (qA & 31) + ((iA + p) & 1);
    int icb = ih * 16 + (l >> 4) * 4;

    float xt[4][9];
    #pragma unroll
    for (int a = 0; a < 4; ++a) {
        const float* xb = x + ((size_t)n * C_IN + icb + a) * (HH * WW);
        #pragma unroll
        for (int di = 0; di < 3; ++di) {
            int ii = iA + di - 1;
            #pragma unroll
            for (int dj = 0; dj < 3; ++dj) {
                int jj = jA + dj - 1;
                bool ok = ((unsigned)ii < 64u) && ((unsigned)jj < 64u);
                xt[a][di * 3 + dj] = ok ? xb[ii * WW + jj] : 0.f;
            }
        }
    }

    const short8v* Bq = (const short8v*)Bpk;
    if (p == 0) aeg_gemm<0>(xt, Bq, cs, ih, grp, l);
    else        aeg_gemm<1>(xt, Bq, cs, ih, grp, l);

    __syncthreads();

    // Coalesced atomic write-out: consecutive lanes -> consecutive dwords.
    #pragma unroll
    for (int iter = 0; iter < 16; ++iter) {
        int f  = iter * 512 + tid;
        int oc = f >> 7;
        int rr = f & 127;
        int ii = rr >> 6;
        int jj = rr & 63;
        float v = cs[oc * 130 + rr];
        ATOMIC_FADD(out + (((size_t)n * C_OUT + oc) * HH + (i0 + ii)) * WW + jj, v);
    }
}

extern "C" void kernel_launch(void* const* d_in, const int* in_sizes, int n_in,
                              void* d_out, int out_size, void* d_ws, size_t ws_size,
                              hipStream_t stream) {
    const float* x = (const float*)d_in[0];
    const float* w = (const float*)d_in[1];
    float* out = (float*)d_out;
    unsigned short* Bpk = (unsigned short*)d_ws;   // 147,456 bytes

    hipMemsetAsync(out, 0, (size_t)out_size * sizeof(float), stream);
    wprod_pack<<<16, 256, 0, stream>>>(w, Bpk);
    aeg_mfma<<<512, 512, 0, stream>>>(x, Bpk, out);
}

// Round 10
// 24.577 us; speedup vs baseline: 1.4356x; 1.4356x over previous
//
#include <hip/hip_runtime.h>
#include <hip/hip_bf16.h>

#define C_IN  32
#define C_OUT 64
#define HH    64
#define WW    64

typedef __attribute__((ext_vector_type(8))) short short8v;
typedef __attribute__((ext_vector_type(4))) float f32x4;

static __device__ __forceinline__ unsigned short f2bf(float f) {
    unsigned u = __builtin_bit_cast(unsigned, f);
    unsigned r = (u + 0x7FFFu + ((u >> 16) & 1u)) >> 16;   // RNE
    return (unsigned short)r;
}
static __device__ __forceinline__ float bf2f(unsigned short b) {
    unsigned u = ((unsigned)b) << 16;
    return __builtin_bit_cast(float, u);
}

// ---------------------------------------------------------------------------
// Weight-product + B-fragment pack (cold kernel, layout unchanged).
// W~_k = Ew(k) * (w_k if (p+k) odd), Ew(k) = prod_{j>=k, (p+j) even} w_j
// Bpk[p][part(h=0,l=1)][k(9)][octile(4)][lane(64)][j(8)]  (bf16)
//   lane = (ic>>3)*16 + (oc&15), j = ic&7, octile = oc>>4
// Per-parity half = 36864 shorts = 73728 B (contiguous).
// ---------------------------------------------------------------------------
__global__ void wprod_pack(const float* __restrict__ w, unsigned short* __restrict__ Bpk) {
    int t = blockIdx.x * 256 + threadIdx.x;
    if (t >= 2 * C_IN * C_OUT) return;
    int oc = t & 63;
    int ic = (t >> 6) & 31;
    int p  = t >> 11;
    const float* wp = w + (oc * C_IN + ic) * 9;
    float W[9];
    float Ew = 1.f;
    #pragma unroll
    for (int k = 8; k >= 0; --k) {
        float wk = wp[k];
        if (((p + k) & 1) == 0) { Ew *= wk; W[k] = Ew; }
        else                    { W[k] = wk * Ew; }
    }
    int lane = ((ic >> 3) << 4) + (oc & 15);
    int j    = ic & 7;
    int oct  = oc >> 4;
    #pragma unroll
    for (int k = 0; k < 9; ++k) {
        unsigned short hi = f2bf(W[k]);
        unsigned short lo = f2bf(W[k] - bf2f(hi));
        size_t ih = ((((size_t)(p * 2 + 0) * 9 + k) * 4 + oct) * 64 + lane) * 8 + j;
        size_t il = ((((size_t)(p * 2 + 1) * 9 + k) * 4 + oct) * 64 + lane) * 8 + j;
        Bpk[ih] = hi;
        Bpk[il] = lo;
    }
}

// ---------------------------------------------------------------------------
// GEMM body (parity compile-time). xt[a][k] -> X~ (suffix products); per-k:
// native-cast bf16 hi/lo A-frag, 4 octiles x 3-term MFMA with B-frags from
// LDS (ds_read_b128, contiguous, 2-way alias = free).
// C = Xh*Wh + Xl*Wh + Xh*Wl  (Xl*Wl ~ 2^-18, dropped).
// ---------------------------------------------------------------------------
template<int P>
__device__ __forceinline__ void aeg_gemm(
    float (&xt)[8][9], const short8v* __restrict__ Bq,
    float* __restrict__ out, int n, int i0, int grp, int l)
{
    // X~: suffix products of odd-step x's; even steps multiply own x.
    #pragma unroll
    for (int a = 0; a < 8; ++a) {
        float Ox = 1.f;
        #pragma unroll
        for (int k = 8; k >= 0; --k) {
            if (((P + k) & 1) == 1) { Ox *= xt[a][k]; xt[a][k] = Ox; }
            else                    { xt[a][k] = xt[a][k] * Ox; }
        }
    }

    f32x4 acc[4];
    #pragma unroll
    for (int t = 0; t < 4; ++t) acc[t] = (f32x4){0.f, 0.f, 0.f, 0.f};

    #pragma unroll
    for (int k = 0; k < 9; ++k) {
        short8v ah, al;
        #pragma unroll
        for (int a = 0; a < 8; ++a) {
            float v  = xt[a][k];
            __hip_bfloat16 bh = __float2bfloat16(v);          // RNE
            float fh = __bfloat162float(bh);
            __hip_bfloat16 bl = __float2bfloat16(v - fh);
            ah[a] = (short)__builtin_bit_cast(unsigned short, bh);
            al[a] = (short)__builtin_bit_cast(unsigned short, bl);
        }
        #pragma unroll
        for (int t = 0; t < 4; ++t) {
            short8v bh = Bq[((0 * 9 + k) * 4 + t) * 64 + l];   // hi half
            short8v bl = Bq[((1 * 9 + k) * 4 + t) * 64 + l];   // lo half
            acc[t] = __builtin_amdgcn_mfma_f32_16x16x32_bf16(ah, bh, acc[t], 0, 0, 0);
            acc[t] = __builtin_amdgcn_mfma_f32_16x16x32_bf16(al, bh, acc[t], 0, 0, 0);
            acc[t] = __builtin_amdgcn_mfma_f32_16x16x32_bf16(ah, bl, acc[t], 0, 0, 0);
        }
    }

    // Scatter C: row = (l>>4)*4 + r (position), col = l&15 (oc low).
    int colc = l & 15;
    int rgrp = l >> 4;
    #pragma unroll
    for (int t = 0; t < 4; ++t) {
        int oc = t * 16 + colc;
        #pragma unroll
        for (int r = 0; r < 4; ++r) {
            int q = grp * 16 + rgrp * 4 + r;
            int i = i0 + (q >> 5);
            int j = 2 * (q & 31) + ((i + P) & 1);
            out[(((size_t)n * C_OUT + oc) * HH + i) * WW + j] = acc[t][r];
        }
    }
}

// ---------------------------------------------------------------------------
// Main kernel: block = 1 n x 2 rows x 64 cols x ONE parity. 256 threads =
// 4 waves, all of parity pp = bid&1; wave w = M-group grp (16 positions).
// Block stages its parity's 72KB Bpk half into LDS once (contiguous
// dwordx4 copy), then B-frags come from the LDS pipe instead of sweeping
// 147KB through the 32KB L1. x stays in global (32KB slab, now L1-stable).
// Occupancy: 2 blocks/CU (144KB LDS), 2 waves/SIMD (same as round-4 cap).
// ---------------------------------------------------------------------------
__global__ __launch_bounds__(256, 2) void aeg_mfma(
    const float* __restrict__ x, const unsigned short* __restrict__ Bpk,
    float* __restrict__ out)
{
    __shared__ __attribute__((aligned(16))) unsigned short Blds[36864]; // 72KB

    int bid = blockIdx.x;
    int pp  = bid & 1;           // parity (0..1)
    int br  = (bid >> 1) & 31;   // row-block (0..31), 2 rows each
    int n   = bid >> 6;          // batch (0..7)
    int i0  = br * 2;
    int tid = threadIdx.x;

    // Stage this parity's B half: 73728 B = 4608 x 16B, contiguous.
    {
        const f32x4* src = (const f32x4*)(Bpk + (size_t)pp * 36864);
        f32x4* dst = (f32x4*)Blds;
        #pragma unroll
        for (int i = 0; i < 18; ++i)
            dst[i * 256 + tid] = src[i * 256 + tid];
    }
    __syncthreads();

    int w   = __builtin_amdgcn_readfirstlane(tid >> 6);  // wave 0..3
    int grp = w;                 // M-group 0..3
    int l   = tid & 63;

    int qA = grp * 16 + (l & 15);
    int iA = i0 + (qA >> 5);
    int jA = 2 * (qA & 31) + ((iA + pp) & 1);
    int icb = (l >> 4) * 8;

    float xt[8][9];
    #pragma unroll
    for (int a = 0; a < 8; ++a) {
        const float* xb = x + ((size_t)n * C_IN + icb + a) * (HH * WW);
        #pragma unroll
        for (int di = 0; di < 3; ++di) {
            int ii = iA + di - 1;
            #pragma unroll
            for (int dj = 0; dj < 3; ++dj) {
                int jj = jA + dj - 1;
                bool ok = ((unsigned)ii < 64u) && ((unsigned)jj < 64u);
                xt[a][di * 3 + dj] = ok ? xb[ii * WW + jj] : 0.f;
            }
        }
    }

    const short8v* Bq = (const short8v*)Blds;
    if (pp == 0) aeg_gemm<0>(xt, Bq, out, n, i0, grp, l);
    else         aeg_gemm<1>(xt, Bq, out, n, i0, grp, l);
}

extern "C" void kernel_launch(void* const* d_in, const int* in_sizes, int n_in,
                              void* d_out, int out_size, void* d_ws, size_t ws_size,
                              hipStream_t stream) {
    const float* x = (const float*)d_in[0];
    const float* w = (const float*)d_in[1];
    float* out = (float*)d_out;
    unsigned short* Bpk = (unsigned short*)d_ws;   // 147,456 bytes

    wprod_pack<<<16, 256, 0, stream>>>(w, Bpk);
    aeg_mfma<<<512, 256, 0, stream>>>(x, Bpk, out);
}